// Round 12
// baseline (403.742 us; speedup 1.0000x reference)
//
#include <hip/hip_runtime.h>
#include <hip/hip_bf16.h>

#define NNODES 30000
#define NEDGES 480000
#define HC 256
#define NEG_SLOPE 0.2f
#define NPART 8
#define EPP 60000                 // NEDGES / NPART
#define PN (NPART * NNODES)       // 240000
#define SCAN_CHUNK 1024
#define NCHUNK2 235               // ceil(PN / 1024)
#define NCHUNKM 30                // ceil(NNODES / 1024)
#define CPP 235                   // ceil(EPP / 256)
#define NFE 7680000               // NNODES * HC
#define NGX 469                   // ceil(NNODES / 64) gemm blocks per sub-GEMM
#define AGG_NB 7500               // ceil(NNODES / 4)

typedef _Float16 half8 __attribute__((ext_vector_type(8)));
typedef _Float16 h4v __attribute__((ext_vector_type(4)));
typedef _Float16 h2 __attribute__((ext_vector_type(2)));
typedef float floatx4 __attribute__((ext_vector_type(4)));

// ---------------- prep: weight transpose+cvt (blocks 0..511) | edge histogram (rest) ----------------

__global__ void prep_kernel(const float* __restrict__ Wl, const float* __restrict__ Wr,
                            _Float16* __restrict__ WtL, _Float16* __restrict__ WtR,
                            const int* __restrict__ ei, int* __restrict__ deg_dst,
                            int* __restrict__ deg_src) {
    __shared__ float sh[32][33];
    int b = blockIdx.x;
    if (b < 512) {
        int e = b >> 6;
        int r0 = ((b >> 3) & 7) * 32, c0 = (b & 7) * 32;
        const float* W = (e < 4) ? Wl + (size_t)e * 65536 : Wr + (size_t)(e - 4) * 65536;
        _Float16* Wt = (e < 4) ? WtL + (size_t)e * 65536 : WtR + (size_t)(e - 4) * 65536;
        int x = threadIdx.x & 31, y = threadIdx.x >> 5;  // 32 x 8
#pragma unroll
        for (int j = 0; j < 4; j++) {
            int r = y + j * 8;
            sh[r][x] = W[(size_t)(r0 + r) * 256 + c0 + x];
        }
        __syncthreads();
#pragma unroll
        for (int j = 0; j < 4; j++) {
            int nn = y + j * 8;
            Wt[(size_t)(c0 + nn) * 256 + r0 + x] = (_Float16)sh[x][nn];
        }
    } else {
        b -= 512;
        int p = b & 7, c = b >> 3;
        int idx = c * 256 + threadIdx.x;
        if (idx >= EPP) return;
        int e = p * EPP + idx;
        int s = ei[e];
        int d = ei[NEDGES + e];
        atomicAdd(&deg_dst[p * NNODES + d], 1);
        atomicAdd(&deg_src[p * NNODES + s], 1);
    }
}

// ---------------- scans ----------------

__global__ void scanA_kernel(const int* __restrict__ deg_dst, const int* __restrict__ deg_src,
                             int* __restrict__ cur_dst, int* __restrict__ cur_src,
                             int* __restrict__ mrpl_dst, int* __restrict__ mrpl_src,
                             int* __restrict__ bsum) {
    __shared__ int sh[SCAN_CHUNK];
    const int y = blockIdx.y;
    const int nelem = (y < 2) ? PN : NNODES;
    if (blockIdx.x * SCAN_CHUNK >= nelem) return;
    int t = threadIdx.x;
    int gid = blockIdx.x * SCAN_CHUNK + t;
    int v = 0;
    if (gid < nelem) {
        if (y == 0) v = deg_dst[gid];
        else if (y == 1) v = deg_src[gid];
        else {
            const int* deg = (y == 2) ? deg_dst : deg_src;
#pragma unroll
            for (int p = 0; p < NPART; p++) v += deg[p * NNODES + gid];
        }
    }
    sh[t] = v;
    __syncthreads();
    for (int off = 1; off < SCAN_CHUNK; off <<= 1) {
        int u = (t >= off) ? sh[t - off] : 0;
        __syncthreads();
        sh[t] += u;
        __syncthreads();
    }
    if (gid < nelem) {
        if (y < 2) ((y == 0) ? cur_dst : cur_src)[gid] = sh[t] - v;
        else ((y == 2) ? mrpl_dst : mrpl_src)[gid + 1] = sh[t];
    }
    if (t == SCAN_CHUNK - 1) bsum[y * 256 + blockIdx.x] = sh[t];
}

__global__ void scan2_kernel(int* __restrict__ bsum) {
    int t = threadIdx.x;
    if (t < 4) {
        int cnt = (t < 2) ? NCHUNK2 : NCHUNKM;
        int run = 0;
        for (int i = 0; i < cnt; i++) {
            int v = bsum[t * 256 + i];
            bsum[t * 256 + i] = run;
            run += v;
        }
    }
}

// ---------------- GEMM body (BK=32, reg-prefetch, LDS epilogue) ----------------

__device__ inline half8 ldA8(const _Float16* p) { return *(const half8*)p; }
__device__ inline half8 ldA8(const float* p) {
    float4 a = *(const float4*)p;
    float4 b = *(const float4*)(p + 4);
    half8 r = {(_Float16)a.x, (_Float16)a.y, (_Float16)a.z, (_Float16)a.w,
               (_Float16)b.x, (_Float16)b.y, (_Float16)b.z, (_Float16)b.w};
    return r;
}

#define EPI_STRIDE 264  // halfs

template <typename AT>
__device__ __forceinline__ void gemm_body(int bx, const AT* __restrict__ A,
                                          const _Float16* __restrict__ Wt,
                                          const float* __restrict__ bvec,
                                          _Float16* __restrict__ C, _Float16* sh) {
    _Float16* As = sh;
    _Float16* Bs = sh + 2048;

    const int t = threadIdx.x;
    const int lane = t & 63, w = t >> 6;
    const int m0 = bx * 64;
    const int rl = lane & 15, ch = lane >> 4;
    const int ar = t >> 2, ac = t & 3;

    floatx4 acc[4][4] = {};

    half8 av = {};
    {
        int gr = m0 + ar;
        if (gr < NNODES) av = ldA8(A + (size_t)gr * 256 + ac * 8);
    }
    half8 bv[4];
#pragma unroll
    for (int j = 0; j < 4; j++)
        bv[j] = *(const half8*)(Wt + (size_t)(ar + j * 64) * 256 + ac * 8);

    for (int k0 = 0; k0 < 256; k0 += 32) {
        __syncthreads();
        *(half8*)(As + ar * 32 + (ac ^ ((ar >> 1) & 3)) * 8) = av;
#pragma unroll
        for (int j = 0; j < 4; j++) {
            int n = ar + j * 64;
            *(half8*)(Bs + n * 32 + (ac ^ ((n >> 1) & 3)) * 8) = bv[j];
        }
        __syncthreads();

        if (k0 + 32 < 256) {
            int gr = m0 + ar;
            if (gr < NNODES) av = ldA8(A + (size_t)gr * 256 + (k0 + 32) + ac * 8);
#pragma unroll
            for (int j = 0; j < 4; j++)
                bv[j] = *(const half8*)(Wt + (size_t)(ar + j * 64) * 256 + (k0 + 32) + ac * 8);
        }

        half8 a[4], b[4];
#pragma unroll
        for (int fm = 0; fm < 4; fm++) {
            int r = fm * 16 + rl;
            a[fm] = *(const half8*)(As + r * 32 + (ch ^ ((r >> 1) & 3)) * 8);
        }
#pragma unroll
        for (int fn = 0; fn < 4; fn++) {
            int n = w * 64 + fn * 16 + rl;
            b[fn] = *(const half8*)(Bs + n * 32 + (ch ^ ((n >> 1) & 3)) * 8);
        }
#pragma unroll
        for (int fm = 0; fm < 4; fm++)
#pragma unroll
            for (int fn = 0; fn < 4; fn++)
                acc[fm][fn] = __builtin_amdgcn_mfma_f32_16x16x32_f16(a[fm], b[fn], acc[fm][fn], 0, 0, 0);
    }

    float bb[4];
#pragma unroll
    for (int fn = 0; fn < 4; fn++) bb[fn] = bvec[w * 64 + fn * 16 + rl];

#pragma unroll
    for (int hh = 0; hh < 2; hh++) {
        __syncthreads();
#pragma unroll
        for (int f2 = 0; f2 < 2; f2++) {
            int fm = hh * 2 + f2;
#pragma unroll
            for (int fn = 0; fn < 4; fn++) {
                int colb = w * 64 + fn * 16 + rl;
#pragma unroll
                for (int j = 0; j < 4; j++) {
                    int lr = f2 * 16 + ch * 4 + j;  // 0..31
                    sh[lr * EPI_STRIDE + colb] = (_Float16)(acc[fm][fn][j] + bb[fn]);
                }
            }
        }
        __syncthreads();
        int lr = t >> 3;            // 0..31
        int cseg = (t & 7) * 32;    // 8 segments x 32 cols (64B)
        int gr = m0 + hh * 32 + lr;
        if (gr < NNODES) {
#pragma unroll
            for (int q = 0; q < 4; q++)
                *(half8*)(C + (size_t)gr * 256 + cseg + q * 8) =
                    *(const half8*)(sh + lr * EPI_STRIDE + cseg + q * 8);
        }
    }
}

// ---------------- agg body (2 edges/wave, 8ch/lane) ----------------

__device__ __forceinline__ void edge_body(half8 hv, half8 hrv, const h2* att2,
                                          float* acc, float& denom, bool valid) {
    const h2 negv = {(_Float16)NEG_SLOPE, (_Float16)NEG_SLOPE};
    const h2* hvp = (const h2*)&hv;
    const h2* hrp = (const h2*)&hrv;
    float v = 0.f;
#pragma unroll
    for (int k = 0; k < 4; k++) {
        h2 x = hvp[k] + hrp[k];
        h2 lk = __builtin_elementwise_max(x, x * negv);
        v = __builtin_amdgcn_fdot2(lk, att2[k], v, false);
    }
    v += __shfl_xor(v, 1);
    v += __shfl_xor(v, 2);
    float pe = __expf(v);
    if (!valid) pe = 0.f;
    denom += pe;
#pragma unroll
    for (int k = 0; k < 8; k++) acc[k] = fmaf((float)hv[k], pe, acc[k]);
}

__device__ inline void store8(float* p, const float* o) {
    floatx4 v0 = {o[0], o[1], o[2], o[3]};
    floatx4 v1 = {o[4], o[5], o[6], o[7]};
    *(floatx4*)p = v0;
    *(floatx4*)(p + 4) = v1;
}
__device__ inline void store8(_Float16* p, const float* o) {
    half8 h = {(_Float16)o[0], (_Float16)o[1], (_Float16)o[2], (_Float16)o[3],
               (_Float16)o[4], (_Float16)o[5], (_Float16)o[6], (_Float16)o[7]};
    *(half8*)p = h;
}

template <typename OT>
__device__ __forceinline__ void agg_body(int bx, const _Float16* __restrict__ hl,
                                         const _Float16* __restrict__ hr,
                                         const int* __restrict__ mrp,
                                         const unsigned short* __restrict__ mcol,
                                         const float* __restrict__ attz,
                                         const float* __restrict__ biasz,
                                         OT* __restrict__ out, int do_relu) {
    int wave = threadIdx.x >> 6;
    int lane = threadIdx.x & 63;
    int n = bx * 4 + wave;
    if (n >= NNODES) return;
    int h = lane >> 5;       // edge parity within the wave
    int cl = lane & 31;      // channel block (8 channels)
    int c8 = cl << 3;

    const _Float16* hlc = hl + c8;
    half8 hrv = *(const half8*)(hr + (size_t)n * HC + c8);
    float attf[8];
    *(float4*)(attf) = *(const float4*)(attz + c8);
    *(float4*)(attf + 4) = *(const float4*)(attz + c8 + 4);
    h2 att2[4];
#pragma unroll
    for (int k = 0; k < 4; k++) att2[k] = h2{(_Float16)attf[2 * k], (_Float16)attf[2 * k + 1]};

    float acc[8] = {};
    float denom = 0.f;
    int beg = mrp[n], end = mrp[n + 1];

    int i = beg;
    for (; i + 4 <= end; i += 4) {
        int s0 = (int)mcol[i + h];
        int s1 = (int)mcol[i + 2 + h];
        half8 hv0 = *(const half8*)(hlc + ((size_t)s0 << 8));
        half8 hv1 = *(const half8*)(hlc + ((size_t)s1 << 8));
        edge_body(hv0, hrv, att2, acc, denom, true);
        edge_body(hv1, hrv, att2, acc, denom, true);
    }
    for (; i < end; i += 2) {
        int ei = i + h;
        bool valid = ei < end;
        int s0 = (int)mcol[valid ? ei : end - 1];
        half8 hv0 = *(const half8*)(hlc + ((size_t)s0 << 8));
        edge_body(hv0, hrv, att2, acc, denom, valid);
    }

#pragma unroll
    for (int k = 0; k < 8; k++) acc[k] += __shfl_xor(acc[k], 32);
    denom += __shfl_xor(denom, 32);

    if (lane < 32) {
        float inv = 1.f / (denom + 1e-16f);
        float o[8];
        float b8[8];
        *(float4*)(b8) = *(const float4*)(biasz + c8);
        *(float4*)(b8 + 4) = *(const float4*)(biasz + c8 + 4);
#pragma unroll
        for (int k = 0; k < 8; k++) {
            o[k] = acc[k] * inv + b8[k];
            if (do_relu) o[k] = fmaxf(o[k], 0.f);
        }
        store8(out + (size_t)n * HC + c8, o);
    }
}

// ---------------- fused kernels ----------------
// fill + layer-0 gemm y=0 (hl0 = s@Wl[0] -> slot0), y=1 (hr0 = t@Wr[0] -> slot1)
__global__ void __launch_bounds__(256)
fillgemm_kernel(const int* __restrict__ ei, int* __restrict__ cur_dst, int* __restrict__ cur_src,
                const int* __restrict__ bsum, unsigned short* __restrict__ col_dst,
                unsigned short* __restrict__ col_src,
                const float* __restrict__ s, const float* __restrict__ t,
                const _Float16* __restrict__ WtL, const _Float16* __restrict__ WtR,
                const float* __restrict__ bl, const float* __restrict__ br,
                _Float16* __restrict__ hbase) {
    __shared__ __align__(16) _Float16 sh[10240];
    int b = blockIdx.x;
    if (b < NPART * CPP) {
        int p = b & 7, c = b >> 3;
        int idx = c * 256 + threadIdx.x;
        if (idx >= EPP) return;
        int e = p * EPP + idx;
        int ss = ei[e];
        int d = ei[NEDGES + e];
        int i0 = p * NNODES + d;
        int p0 = atomicAdd(&cur_dst[i0], 1) + bsum[i0 >> 10];
        col_dst[p0] = (unsigned short)ss;
        int i1 = p * NNODES + ss;
        int p1 = atomicAdd(&cur_src[i1], 1) + bsum[256 + (i1 >> 10)];
        col_src[p1] = (unsigned short)d;
    } else {
        int g = b - NPART * CPP;
        if (g < NGX) gemm_body<float>(g, s, WtL, bl, hbase, sh);
        else gemm_body<float>(g - NGX, t, WtR, br, hbase + (size_t)NFE, sh);
    }
}

// merge + layer-0 gemm y=2 (hl1 = t@Wl[1] -> slot2), y=3 (hr1 = s@Wr[1] -> slot3)
__global__ void __launch_bounds__(256)
mergegemm_kernel(const int* __restrict__ deg_dst, const int* __restrict__ deg_src,
                 const int* __restrict__ cur_dst, const int* __restrict__ cur_src,
                 const int* __restrict__ mrpl_dst, const int* __restrict__ mrpl_src,
                 int* __restrict__ mrpf_dst, int* __restrict__ mrpf_src,
                 const int* __restrict__ bsum,
                 const unsigned short* __restrict__ col_dst,
                 const unsigned short* __restrict__ col_src,
                 unsigned short* __restrict__ mcol_dst, unsigned short* __restrict__ mcol_src,
                 const float* __restrict__ s, const float* __restrict__ t,
                 const _Float16* __restrict__ WtL, const _Float16* __restrict__ WtR,
                 const float* __restrict__ bl, const float* __restrict__ br,
                 _Float16* __restrict__ hbase) {
    __shared__ __align__(16) _Float16 sh[10240];
    int b = blockIdx.x;
    if (b < 236) {
        const int z = (b >= 118);
        const int bx = z ? b - 118 : b;
        const int* deg = z ? deg_src : deg_dst;
        const int* cur = z ? cur_src : cur_dst;
        const int* mrpl = z ? mrpl_src : mrpl_dst;
        int* mrpf = z ? mrpf_src : mrpf_dst;
        const unsigned short* col = z ? col_src : col_dst;
        unsigned short* mcol = z ? mcol_src : mcol_dst;
        int n = bx * 256 + threadIdx.x;
        if (n >= NNODES) return;
        int dv[NPART];
        int mdeg = 0;
#pragma unroll
        for (int p = 0; p < NPART; p++) {
            dv[p] = deg[p * NNODES + n];
            mdeg += dv[p];
        }
        int start = mrpl[n + 1] + bsum[(2 + z) * 256 + (n >> 10)] - mdeg;
        mrpf[n] = start;
        if (n == NNODES - 1) mrpf[NNODES] = NEDGES;
        int w = start;
#pragma unroll
        for (int p = 0; p < NPART; p++) {
            int i = p * NNODES + n;
            int egl = cur[i] + bsum[z * 256 + (i >> 10)];
            for (int k = egl - dv[p]; k < egl; k++) mcol[w++] = col[k];
        }
    } else {
        int g = b - 236;
        if (g < NGX) gemm_body<float>(g, t, WtL + 65536, bl + 256, hbase + (size_t)2 * NFE, sh);
        else gemm_body<float>(g - NGX, s, WtR + 65536, br + 256, hbase + (size_t)3 * NFE, sh);
    }
}

// layer-0 agg z=0 only (reads slots 0,1 -> os16)
__global__ void __launch_bounds__(256)
agg0_kernel(const _Float16* __restrict__ hbase, const int* __restrict__ mrp_dst,
            const unsigned short* __restrict__ mcol_dst, const float* __restrict__ att,
            const float* __restrict__ bias, _Float16* __restrict__ os16) {
    agg_body<_Float16>(blockIdx.x, hbase, hbase + (size_t)NFE, mrp_dst, mcol_dst, att, bias, os16, 1);
}

// layer-0 agg z=1 (reads slots 2,3 -> ot16)  ||  layer-1 gemm on os16:
//   hl2 = os16@Wl[2] -> slot0 ; hr3 = os16@Wr[3] -> slot1
__global__ void __launch_bounds__(256)
aggz1gemm_kernel(const _Float16* __restrict__ hbase, const int* __restrict__ mrp_src,
                 const unsigned short* __restrict__ mcol_src, const float* __restrict__ att,
                 const float* __restrict__ bias, _Float16* __restrict__ ot16,
                 const _Float16* __restrict__ os16,
                 const _Float16* __restrict__ WtL, const _Float16* __restrict__ WtR,
                 const float* __restrict__ bl, const float* __restrict__ br,
                 _Float16* __restrict__ hb) {
    __shared__ __align__(16) _Float16 sh[10240];
    int b = blockIdx.x;
    if (b < AGG_NB) {
        agg_body<_Float16>(b, hbase + (size_t)2 * NFE, hbase + (size_t)3 * NFE,
                           mrp_src, mcol_src, att + 256, bias + 256, ot16, 1);
    } else {
        int g = b - AGG_NB;
        if (g < NGX) gemm_body<_Float16>(g, os16, WtL + 2 * 65536, bl + 2 * 256, hb, sh);
        else gemm_body<_Float16>(g - NGX, os16, WtR + 3 * 65536, br + 3 * 256, hb + (size_t)NFE, sh);
    }
}

// layer-1 gemm on ot16: hr2 = ot16@Wr[2] -> slot2 ; hl3 = ot16@Wl[3] -> slot3
__global__ void __launch_bounds__(256)
gemm1b_kernel(const _Float16* __restrict__ ot16,
              const _Float16* __restrict__ WtL, const _Float16* __restrict__ WtR,
              const float* __restrict__ bl, const float* __restrict__ br,
              _Float16* __restrict__ hbase) {
    __shared__ __align__(16) _Float16 sh[10240];
    if (blockIdx.y == 0)
        gemm_body<_Float16>(blockIdx.x, ot16, WtR + 2 * 65536, br + 2 * 256,
                            hbase + (size_t)2 * NFE, sh);
    else
        gemm_body<_Float16>(blockIdx.x, ot16, WtL + 3 * 65536, bl + 3 * 256,
                            hbase + (size_t)3 * NFE, sh);
}

// layer-1 agg, both directions. slots: z=0 hl=0, hr=2 ; z=1 hl=3, hr=1
__global__ void __launch_bounds__(256)
agg1_kernel(const _Float16* __restrict__ hbase, const int* __restrict__ mrp_dst,
            const unsigned short* __restrict__ mcol_dst, const int* __restrict__ mrp_src,
            const unsigned short* __restrict__ mcol_src, const float* __restrict__ att,
            const float* __restrict__ bias, float* __restrict__ out) {
    if (blockIdx.y == 0)
        agg_body<float>(blockIdx.x, hbase, hbase + (size_t)2 * NFE, mrp_dst, mcol_dst,
                        att + 2 * 256, bias + 2 * 256, out, 0);
    else
        agg_body<float>(blockIdx.x, hbase + (size_t)3 * NFE, hbase + (size_t)NFE,
                        mrp_src, mcol_src, att + 3 * 256, bias + 3 * 256, out + (size_t)NFE, 0);
}

// ---------------- launch ----------------

extern "C" void kernel_launch(void* const* d_in, const int* in_sizes, int n_in,
                              void* d_out, int out_size, void* d_ws, size_t ws_size,
                              hipStream_t stream) {
    const float* s = (const float*)d_in[0];
    const float* t = (const float*)d_in[1];
    const float* Wl = (const float*)d_in[2];
    const float* bl = (const float*)d_in[3];
    const float* Wr = (const float*)d_in[4];
    const float* br = (const float*)d_in[5];
    const float* att = (const float*)d_in[6];
    const float* bias = (const float*)d_in[7];
    const int* ei = (const int*)d_in[8];
    float* out = (float*)d_out;

    const size_t NF = (size_t)NFE;

    // workspace layout
    _Float16* os16 = (_Float16*)d_ws;         // NF
    _Float16* ot16 = os16 + NF;               // NF
    _Float16* hbase = ot16 + NF;              // 4*NF
    _Float16* WtL = hbase + 4 * NF;           // 4*65536
    _Float16* WtR = WtL + 4 * 65536;          // 4*65536
    int* deg_dst = (int*)(WtR + 4 * 65536);   // PN
    int* deg_src = deg_dst + PN;              // PN
    int* cur_dst = deg_src + PN;              // PN
    int* cur_src = cur_dst + PN;              // PN
    int* mrpl_dst = cur_src + PN;             // N+1
    int* mrpl_src = mrpl_dst + (NNODES + 1);  // N+1
    int* mrpf_dst = mrpl_src + (NNODES + 1);  // N+1
    int* mrpf_src = mrpf_dst + (NNODES + 1);  // N+1
    int* bsum = mrpf_src + (NNODES + 1);      // 1024
    unsigned short* col_dst = (unsigned short*)(bsum + 1024);  // E
    unsigned short* col_src = col_dst + NEDGES;                // E
    unsigned short* mcol_dst = col_src + NEDGES;               // E
    unsigned short* mcol_src = mcol_dst + NEDGES;              // E

    // ---- CSR build + weight prep ----
    hipMemsetAsync(deg_dst, 0, 2 * PN * sizeof(int), stream);
    prep_kernel<<<512 + NPART * CPP, 256, 0, stream>>>(Wl, Wr, WtL, WtR, ei, deg_dst, deg_src);
    scanA_kernel<<<dim3(NCHUNK2, 4), SCAN_CHUNK, 0, stream>>>(deg_dst, deg_src, cur_dst, cur_src,
                                                              mrpl_dst, mrpl_src, bsum);
    scan2_kernel<<<1, 64, 0, stream>>>(bsum);

    // ---- fill || gemm0a ----
    fillgemm_kernel<<<NPART * CPP + 2 * NGX, 256, 0, stream>>>(
        ei, cur_dst, cur_src, bsum, col_dst, col_src, s, t, WtL, WtR, bl, br, hbase);
    // ---- merge || gemm0b ----
    mergegemm_kernel<<<236 + 2 * NGX, 256, 0, stream>>>(
        deg_dst, deg_src, cur_dst, cur_src, mrpl_dst, mrpl_src, mrpf_dst, mrpf_src, bsum,
        col_dst, col_src, mcol_dst, mcol_src, s, t, WtL, WtR, bl, br, hbase);

    // ---- layer 0 agg z=0 ----
    agg0_kernel<<<AGG_NB, 256, 0, stream>>>(hbase, mrpf_dst, mcol_dst, att, bias, os16);
    // ---- layer 0 agg z=1 || layer 1 gemm on os16 ----
    aggz1gemm_kernel<<<AGG_NB + 2 * NGX, 256, 0, stream>>>(
        hbase, mrpf_src, mcol_src, att, bias, ot16, os16, WtL, WtR, bl, br, hbase);
    // ---- layer 1 gemm on ot16 ----
    gemm1b_kernel<<<dim3(NGX, 2), 256, 0, stream>>>(ot16, WtL, WtR, bl, br, hbase);
    // ---- layer 1 agg (both dirs) ----
    agg1_kernel<<<dim3(AGG_NB, 2), 256, 0, stream>>>(hbase, mrpf_dst, mcol_dst, mrpf_src,
                                                     mcol_src, att, bias, out);
}

// Round 13
// 366.141 us; speedup vs baseline: 1.1027x; 1.1027x over previous
//
#include <hip/hip_runtime.h>
#include <hip/hip_bf16.h>

#define NNODES 30000
#define NEDGES 480000
#define HC 256
#define NEG_SLOPE 0.2f
#define NPART 8
#define EPP 60000                 // NEDGES / NPART
#define PN (NPART * NNODES)       // 240000
#define SCAN_CHUNK 1024
#define NCHUNK2 235               // ceil(PN / 1024)
#define NCHUNKM 30                // ceil(NNODES / 1024)
#define CPP 235                   // ceil(EPP / 256)
#define NFE 7680000               // NNODES * HC

typedef _Float16 half8 __attribute__((ext_vector_type(8)));
typedef _Float16 h4v __attribute__((ext_vector_type(4)));
typedef _Float16 h2 __attribute__((ext_vector_type(2)));
typedef float floatx4 __attribute__((ext_vector_type(4)));

// ---------------- prep: weight transpose+cvt (blocks 0..511) | edge histogram (rest) ----------------

__global__ void prep_kernel(const float* __restrict__ Wl, const float* __restrict__ Wr,
                            _Float16* __restrict__ WtL, _Float16* __restrict__ WtR,
                            const int* __restrict__ ei, int* __restrict__ deg_dst,
                            int* __restrict__ deg_src) {
    __shared__ float sh[32][33];
    int b = blockIdx.x;
    if (b < 512) {
        int e = b >> 6;
        int r0 = ((b >> 3) & 7) * 32, c0 = (b & 7) * 32;
        const float* W = (e < 4) ? Wl + (size_t)e * 65536 : Wr + (size_t)(e - 4) * 65536;
        _Float16* Wt = (e < 4) ? WtL + (size_t)e * 65536 : WtR + (size_t)(e - 4) * 65536;
        int x = threadIdx.x & 31, y = threadIdx.x >> 5;  // 32 x 8
#pragma unroll
        for (int j = 0; j < 4; j++) {
            int r = y + j * 8;
            sh[r][x] = W[(size_t)(r0 + r) * 256 + c0 + x];
        }
        __syncthreads();
#pragma unroll
        for (int j = 0; j < 4; j++) {
            int nn = y + j * 8;
            Wt[(size_t)(c0 + nn) * 256 + r0 + x] = (_Float16)sh[x][nn];
        }
    } else {
        b -= 512;
        int p = b & 7, c = b >> 3;
        int idx = c * 256 + threadIdx.x;
        if (idx >= EPP) return;
        int e = p * EPP + idx;
        int s = ei[e];
        int d = ei[NEDGES + e];
        atomicAdd(&deg_dst[p * NNODES + d], 1);
        atomicAdd(&deg_src[p * NNODES + s], 1);
    }
}

// ---------------- scans ----------------
// y=0: deg_dst -> cur_dst (local exclusive); y=1: deg_src -> cur_src
// y=2: sum_p deg_dst -> mrpl_dst[gid+1] (local inclusive); y=3: same for src

__global__ void scanA_kernel(const int* __restrict__ deg_dst, const int* __restrict__ deg_src,
                             int* __restrict__ cur_dst, int* __restrict__ cur_src,
                             int* __restrict__ mrpl_dst, int* __restrict__ mrpl_src,
                             int* __restrict__ bsum) {
    __shared__ int sh[SCAN_CHUNK];
    const int y = blockIdx.y;
    const int nelem = (y < 2) ? PN : NNODES;
    if (blockIdx.x * SCAN_CHUNK >= nelem) return;
    int t = threadIdx.x;
    int gid = blockIdx.x * SCAN_CHUNK + t;
    int v = 0;
    if (gid < nelem) {
        if (y == 0) v = deg_dst[gid];
        else if (y == 1) v = deg_src[gid];
        else {
            const int* deg = (y == 2) ? deg_dst : deg_src;
#pragma unroll
            for (int p = 0; p < NPART; p++) v += deg[p * NNODES + gid];
        }
    }
    sh[t] = v;
    __syncthreads();
    for (int off = 1; off < SCAN_CHUNK; off <<= 1) {
        int u = (t >= off) ? sh[t - off] : 0;
        __syncthreads();
        sh[t] += u;
        __syncthreads();
    }
    if (gid < nelem) {
        if (y < 2) ((y == 0) ? cur_dst : cur_src)[gid] = sh[t] - v;
        else ((y == 2) ? mrpl_dst : mrpl_src)[gid + 1] = sh[t];
    }
    if (t == SCAN_CHUNK - 1) bsum[y * 256 + blockIdx.x] = sh[t];
}

__global__ void scan2_kernel(int* __restrict__ bsum) {
    int t = threadIdx.x;
    if (t < 4) {
        int cnt = (t < 2) ? NCHUNK2 : NCHUNKM;
        int run = 0;
        for (int i = 0; i < cnt; i++) {
            int v = bsum[t * 256 + i];
            bsum[t * 256 + i] = run;
            run += v;
        }
    }
}

// ---------------- fill (adds chunk base from bsum inline) ----------------

__global__ void fill_kernel(const int* __restrict__ ei, int* __restrict__ cur_dst,
                            int* __restrict__ cur_src, const int* __restrict__ bsum,
                            unsigned short* __restrict__ col_dst,
                            unsigned short* __restrict__ col_src) {
    int p = blockIdx.x & 7, c = blockIdx.x >> 3;
    int idx = c * 256 + threadIdx.x;
    if (idx >= EPP) return;
    int e = p * EPP + idx;
    int s = ei[e];
    int d = ei[NEDGES + e];
    int i0 = p * NNODES + d;
    int p0 = atomicAdd(&cur_dst[i0], 1) + bsum[i0 >> 10];
    col_dst[p0] = (unsigned short)s;
    int i1 = p * NNODES + s;
    int p1 = atomicAdd(&cur_src[i1], 1) + bsum[256 + (i1 >> 10)];
    col_src[p1] = (unsigned short)d;
}

// ---------------- merge (also finalizes mrp) ----------------

__global__ void merge_kernel(const int* __restrict__ deg_dst, const int* __restrict__ deg_src,
                             const int* __restrict__ cur_dst, const int* __restrict__ cur_src,
                             const int* __restrict__ mrpl_dst, const int* __restrict__ mrpl_src,
                             int* __restrict__ mrpf_dst, int* __restrict__ mrpf_src,
                             const int* __restrict__ bsum,
                             const unsigned short* __restrict__ col_dst,
                             const unsigned short* __restrict__ col_src,
                             unsigned short* __restrict__ mcol_dst,
                             unsigned short* __restrict__ mcol_src) {
    const int z = blockIdx.y;
    const int* deg = z ? deg_src : deg_dst;
    const int* cur = z ? cur_src : cur_dst;
    const int* mrpl = z ? mrpl_src : mrpl_dst;
    int* mrpf = z ? mrpf_src : mrpf_dst;
    const unsigned short* col = z ? col_src : col_dst;
    unsigned short* mcol = z ? mcol_src : mcol_dst;
    int n = blockIdx.x * blockDim.x + threadIdx.x;
    if (n >= NNODES) return;
    int dv[NPART];
    int mdeg = 0;
#pragma unroll
    for (int p = 0; p < NPART; p++) {
        dv[p] = deg[p * NNODES + n];
        mdeg += dv[p];
    }
    int start = mrpl[n + 1] + bsum[(2 + z) * 256 + (n >> 10)] - mdeg;
    mrpf[n] = start;
    if (n == NNODES - 1) mrpf[NNODES] = NEDGES;
    int w = start;
#pragma unroll
    for (int p = 0; p < NPART; p++) {
        int i = p * NNODES + n;
        int egl = cur[i] + bsum[z * 256 + (i >> 10)];
        for (int k = egl - dv[p]; k < egl; k++) mcol[w++] = col[k];
    }
}

// ---------------- fp16 MFMA GEMM (BK=32, reg-prefetch, DOUBLE-BUFFERED LDS, LDS epilogue) ----------------
// y=0: hl_a = xs@Wl[e0];  y=1: hr_a = xt@Wr[e0]
// y=2: hl_b = xt@Wl[e1];  y=3: hr_b = xs@Wr[e1]

__device__ inline half8 ldA8(const _Float16* p) { return *(const half8*)p; }
__device__ inline half8 ldA8(const float* p) {
    float4 a = *(const float4*)p;
    float4 b = *(const float4*)(p + 4);
    half8 r = {(_Float16)a.x, (_Float16)a.y, (_Float16)a.z, (_Float16)a.w,
               (_Float16)b.x, (_Float16)b.y, (_Float16)b.z, (_Float16)b.w};
    return r;
}

#define EPI_STRIDE 264  // halfs
#define BUFH 10240      // halfs per LDS buffer (As 2048 + Bs 8192)

template <typename AT>
__global__ void __launch_bounds__(256)
gemm_f16(const AT* __restrict__ xs, const AT* __restrict__ xt,
         const _Float16* __restrict__ WtL, const _Float16* __restrict__ WtR,
         const float* __restrict__ bl, const float* __restrict__ br,
         _Float16* __restrict__ hbase, int e0) {
    const int y = blockIdx.y;
    const int e = e0 + (y >> 1);
    const AT* A = (y == 0 || y == 3) ? xs : xt;
    const bool left = (y & 1) == 0;
    const _Float16* Wt = (left ? WtL : WtR) + (size_t)e * 65536;
    const float* bvec = (left ? bl : br) + (size_t)e * HC;
    _Float16* C = hbase + (size_t)y * NFE;

    __shared__ __align__(16) _Float16 sh[2 * BUFH];  // 40 KB ping-pong; reused by epilogue

    const int t = threadIdx.x;
    const int lane = t & 63, w = t >> 6;
    const int m0 = blockIdx.x * 64;
    const int rl = lane & 15, ch = lane >> 4;
    const int ar = t >> 2, ac = t & 3;

    floatx4 acc[4][4] = {};

    half8 av = {};
    {
        int gr = m0 + ar;
        if (gr < NNODES) av = ldA8(A + (size_t)gr * 256 + ac * 8);
    }
    half8 bv[4];
#pragma unroll
    for (int j = 0; j < 4; j++)
        bv[j] = *(const half8*)(Wt + (size_t)(ar + j * 64) * 256 + ac * 8);

#pragma unroll
    for (int kk = 0; kk < 8; kk++) {
        const int k0 = kk * 32;
        _Float16* As = sh + (kk & 1) * BUFH;
        _Float16* Bs = As + 2048;
        // write this tile into buf[kk&1]; safe: prior reads of this buf completed
        // before the previous iteration's barrier (compiler drains lgkmcnt pre-barrier).
        *(half8*)(As + ar * 32 + (ac ^ ((ar >> 1) & 3)) * 8) = av;
#pragma unroll
        for (int j = 0; j < 4; j++) {
            int n = ar + j * 64;
            *(half8*)(Bs + n * 32 + (ac ^ ((n >> 1) & 3)) * 8) = bv[j];
        }
        __syncthreads();

        if (k0 + 32 < 256) {
            int gr = m0 + ar;
            if (gr < NNODES) av = ldA8(A + (size_t)gr * 256 + (k0 + 32) + ac * 8);
#pragma unroll
            for (int j = 0; j < 4; j++)
                bv[j] = *(const half8*)(Wt + (size_t)(ar + j * 64) * 256 + (k0 + 32) + ac * 8);
        }

        half8 a[4], b[4];
#pragma unroll
        for (int fm = 0; fm < 4; fm++) {
            int r = fm * 16 + rl;
            a[fm] = *(const half8*)(As + r * 32 + (ch ^ ((r >> 1) & 3)) * 8);
        }
#pragma unroll
        for (int fn = 0; fn < 4; fn++) {
            int n = w * 64 + fn * 16 + rl;
            b[fn] = *(const half8*)(Bs + n * 32 + (ch ^ ((n >> 1) & 3)) * 8);
        }
#pragma unroll
        for (int fm = 0; fm < 4; fm++)
#pragma unroll
            for (int fn = 0; fn < 4; fn++)
                acc[fm][fn] = __builtin_amdgcn_mfma_f32_16x16x32_f16(a[fm], b[fn], acc[fm][fn], 0, 0, 0);
    }

    float bb[4];
#pragma unroll
    for (int fn = 0; fn < 4; fn++) bb[fn] = bvec[w * 64 + fn * 16 + rl];

#pragma unroll
    for (int hh = 0; hh < 2; hh++) {
        __syncthreads();
#pragma unroll
        for (int f2 = 0; f2 < 2; f2++) {
            int fm = hh * 2 + f2;
#pragma unroll
            for (int fn = 0; fn < 4; fn++) {
                int colb = w * 64 + fn * 16 + rl;
#pragma unroll
                for (int j = 0; j < 4; j++) {
                    int lr = f2 * 16 + ch * 4 + j;  // 0..31
                    sh[lr * EPI_STRIDE + colb] = (_Float16)(acc[fm][fn][j] + bb[fn]);
                }
            }
        }
        __syncthreads();
        int lr = t >> 3;            // 0..31
        int cseg = (t & 7) * 32;    // 8 segments x 32 cols (64B)
        int gr = m0 + hh * 32 + lr;
        if (gr < NNODES) {
#pragma unroll
            for (int q = 0; q < 4; q++)
                *(half8*)(C + (size_t)gr * 256 + cseg + q * 8) =
                    *(const half8*)(sh + lr * EPI_STRIDE + cseg + q * 8);
        }
    }
}

// ---------------- fused attention + aggregate (2 edges/wave, 8ch/lane) ----------------
// att pre-scaled by log2(e): logit dot lands in log2 domain -> bare exp2f.

__device__ __forceinline__ void edge_body(half8 hv, half8 hrv, const h2* att2,
                                          float* acc, float& denom, bool valid) {
    const h2 negv = {(_Float16)NEG_SLOPE, (_Float16)NEG_SLOPE};
    const h2* hvp = (const h2*)&hv;
    const h2* hrp = (const h2*)&hrv;
    float v = 0.f;
#pragma unroll
    for (int k = 0; k < 4; k++) {
        h2 x = hvp[k] + hrp[k];
        h2 lk = __builtin_elementwise_max(x, x * negv);
        v = __builtin_amdgcn_fdot2(lk, att2[k], v, false);
    }
    v += __shfl_xor(v, 1);
    v += __shfl_xor(v, 2);
    float pe = exp2f(v);
    if (!valid) pe = 0.f;
    denom += pe;
#pragma unroll
    for (int k = 0; k < 8; k++) acc[k] = fmaf((float)hv[k], pe, acc[k]);
}

__device__ inline void store8(float* p, const float* o) {
    floatx4 v0 = {o[0], o[1], o[2], o[3]};
    floatx4 v1 = {o[4], o[5], o[6], o[7]};
    *(floatx4*)p = v0;
    *(floatx4*)(p + 4) = v1;
}
__device__ inline void store8(_Float16* p, const float* o) {
    half8 h = {(_Float16)o[0], (_Float16)o[1], (_Float16)o[2], (_Float16)o[3],
               (_Float16)o[4], (_Float16)o[5], (_Float16)o[6], (_Float16)o[7]};
    *(half8*)p = h;
}

template <typename OT>
__global__ void __launch_bounds__(256)
agg_kernel(const _Float16* __restrict__ hbase,
           const int* __restrict__ mrp_dst, const unsigned short* __restrict__ mcol_dst,
           const int* __restrict__ mrp_src, const unsigned short* __restrict__ mcol_src,
           const float* __restrict__ att, const float* __restrict__ bias,
           OT* __restrict__ out0, OT* __restrict__ out1, int e0, int do_relu) {
    const int z = blockIdx.y;
    const _Float16* hl = hbase + (size_t)z * 2 * NFE;
    const _Float16* hr = hl + NFE;
    const int* mrp = z ? mrp_src : mrp_dst;
    const unsigned short* mcol = z ? mcol_src : mcol_dst;
    const float* attz = att + (size_t)(e0 + z) * HC;
    const float* biasz = bias + (size_t)(e0 + z) * HC;
    OT* out = z ? out1 : out0;

    int wave = threadIdx.x >> 6;
    int lane = threadIdx.x & 63;
    int n = blockIdx.x * 4 + wave;
    if (n >= NNODES) return;
    int h = lane >> 5;       // edge parity within the wave
    int cl = lane & 31;      // channel block (8 channels)
    int c8 = cl << 3;

    const _Float16* hlc = hl + c8;
    half8 hrv = *(const half8*)(hr + (size_t)n * HC + c8);
    float attf[8];
    *(float4*)(attf) = *(const float4*)(attz + c8);
    *(float4*)(attf + 4) = *(const float4*)(attz + c8 + 4);
    h2 att2[4];
#pragma unroll
    for (int k = 0; k < 4; k++)
        att2[k] = h2{(_Float16)(attf[2 * k] * 1.44269504f),
                     (_Float16)(attf[2 * k + 1] * 1.44269504f)};

    float acc[8] = {};
    float denom = 0.f;
    int beg = mrp[n], end = mrp[n + 1];

    int i = beg;
    for (; i + 4 <= end; i += 4) {
        int s0 = (int)mcol[i + h];
        int s1 = (int)mcol[i + 2 + h];
        half8 hv0 = *(const half8*)(hlc + ((size_t)s0 << 8));
        half8 hv1 = *(const half8*)(hlc + ((size_t)s1 << 8));
        edge_body(hv0, hrv, att2, acc, denom, true);
        edge_body(hv1, hrv, att2, acc, denom, true);
    }
    for (; i < end; i += 2) {
        int ei = i + h;
        bool valid = ei < end;
        int s0 = (int)mcol[valid ? ei : end - 1];
        half8 hv0 = *(const half8*)(hlc + ((size_t)s0 << 8));
        edge_body(hv0, hrv, att2, acc, denom, valid);
    }

    // merge the two half-wave partials
#pragma unroll
    for (int k = 0; k < 8; k++) acc[k] += __shfl_xor(acc[k], 32);
    denom += __shfl_xor(denom, 32);

    if (lane < 32) {
        float inv = 1.f / (denom + 1e-16f);
        float o[8];
        float b8[8];
        *(float4*)(b8) = *(const float4*)(biasz + c8);
        *(float4*)(b8 + 4) = *(const float4*)(biasz + c8 + 4);
#pragma unroll
        for (int k = 0; k < 8; k++) {
            o[k] = acc[k] * inv + b8[k];
            if (do_relu) o[k] = fmaxf(o[k], 0.f);
        }
        store8(out + (size_t)n * HC + c8, o);
    }
}

// ---------------- launch ----------------

extern "C" void kernel_launch(void* const* d_in, const int* in_sizes, int n_in,
                              void* d_out, int out_size, void* d_ws, size_t ws_size,
                              hipStream_t stream) {
    const float* s = (const float*)d_in[0];
    const float* t = (const float*)d_in[1];
    const float* Wl = (const float*)d_in[2];
    const float* bl = (const float*)d_in[3];
    const float* Wr = (const float*)d_in[4];
    const float* br = (const float*)d_in[5];
    const float* att = (const float*)d_in[6];
    const float* bias = (const float*)d_in[7];
    const int* ei = (const int*)d_in[8];
    float* out = (float*)d_out;

    const size_t NF = (size_t)NFE;

    // workspace layout
    _Float16* os16 = (_Float16*)d_ws;         // NF
    _Float16* ot16 = os16 + NF;               // NF
    _Float16* hbase = ot16 + NF;              // 4*NF
    _Float16* WtL = hbase + 4 * NF;           // 4*65536
    _Float16* WtR = WtL + 4 * 65536;          // 4*65536
    int* deg_dst = (int*)(WtR + 4 * 65536);   // PN
    int* deg_src = deg_dst + PN;              // PN
    int* cur_dst = deg_src + PN;              // PN
    int* cur_src = cur_dst + PN;              // PN
    int* mrpl_dst = cur_src + PN;             // N+1
    int* mrpl_src = mrpl_dst + (NNODES + 1);  // N+1
    int* mrpf_dst = mrpl_src + (NNODES + 1);  // N+1
    int* mrpf_src = mrpf_dst + (NNODES + 1);  // N+1
    int* bsum = mrpf_src + (NNODES + 1);      // 1024
    unsigned short* col_dst = (unsigned short*)(bsum + 1024);  // E
    unsigned short* col_src = col_dst + NEDGES;                // E
    unsigned short* mcol_dst = col_src + NEDGES;               // E
    unsigned short* mcol_src = mcol_dst + NEDGES;              // E

    // ---- CSR build + weight prep ----
    hipMemsetAsync(deg_dst, 0, 2 * PN * sizeof(int), stream);
    prep_kernel<<<512 + NPART * CPP, 256, 0, stream>>>(Wl, Wr, WtL, WtR, ei, deg_dst, deg_src);
    scanA_kernel<<<dim3(NCHUNK2, 4), SCAN_CHUNK, 0, stream>>>(deg_dst, deg_src, cur_dst, cur_src,
                                                              mrpl_dst, mrpl_src, bsum);
    scan2_kernel<<<1, 64, 0, stream>>>(bsum);
    fill_kernel<<<NPART * CPP, 256, 0, stream>>>(ei, cur_dst, cur_src, bsum, col_dst, col_src);
    merge_kernel<<<dim3(118, 2), 256, 0, stream>>>(deg_dst, deg_src, cur_dst, cur_src,
                                                   mrpl_dst, mrpl_src, mrpf_dst, mrpf_src, bsum,
                                                   col_dst, col_src, mcol_dst, mcol_src);

    dim3 ggemm((NNODES + 63) / 64, 4);
    dim3 gagg((NNODES + 3) / 4, 2);

    // layer 0 (fp32 inputs, relu)
    gemm_f16<float><<<ggemm, 256, 0, stream>>>(s, t, WtL, WtR, bl, br, hbase, 0);
    agg_kernel<_Float16><<<gagg, 256, 0, stream>>>(hbase, mrpf_dst, mcol_dst, mrpf_src, mcol_src,
                                                   att, bias, os16, ot16, 0, 1);
    // layer 1 (fp16 inputs, identity, fp32 out)
    gemm_f16<_Float16><<<ggemm, 256, 0, stream>>>(os16, ot16, WtL, WtR, bl, br, hbase, 2);
    agg_kernel<float><<<gagg, 256, 0, stream>>>(hbase, mrpf_dst, mcol_dst, mrpf_src, mcol_src,
                                                att, bias, out, out + NF, 2, 0);
}

// Round 14
// 361.487 us; speedup vs baseline: 1.1169x; 1.0129x over previous
//
#include <hip/hip_runtime.h>
#include <hip/hip_bf16.h>

#define NNODES 30000
#define NEDGES 480000
#define HC 256
#define NEG_SLOPE 0.2f
#define NPART 8
#define EPP 60000                 // NEDGES / NPART
#define PN (NPART * NNODES)       // 240000
#define SCAN_CHUNK 1024
#define NCHUNK2 235               // ceil(PN / 1024)
#define NCHUNKM 30                // ceil(NNODES / 1024)
#define CPP 235                   // ceil(EPP / 256)
#define NFE 7680000               // NNODES * HC

typedef _Float16 half8 __attribute__((ext_vector_type(8)));
typedef _Float16 h4v __attribute__((ext_vector_type(4)));
typedef _Float16 h2 __attribute__((ext_vector_type(2)));
typedef float floatx4 __attribute__((ext_vector_type(4)));

// ---------------- prep: weight transpose+cvt (blocks 0..511) | edge histogram (rest) ----------------

__global__ void prep_kernel(const float* __restrict__ Wl, const float* __restrict__ Wr,
                            _Float16* __restrict__ WtL, _Float16* __restrict__ WtR,
                            const int* __restrict__ ei, int* __restrict__ deg_dst,
                            int* __restrict__ deg_src) {
    __shared__ float sh[32][33];
    int b = blockIdx.x;
    if (b < 512) {
        int e = b >> 6;
        int r0 = ((b >> 3) & 7) * 32, c0 = (b & 7) * 32;
        const float* W = (e < 4) ? Wl + (size_t)e * 65536 : Wr + (size_t)(e - 4) * 65536;
        _Float16* Wt = (e < 4) ? WtL + (size_t)e * 65536 : WtR + (size_t)(e - 4) * 65536;
        int x = threadIdx.x & 31, y = threadIdx.x >> 5;  // 32 x 8
#pragma unroll
        for (int j = 0; j < 4; j++) {
            int r = y + j * 8;
            sh[r][x] = W[(size_t)(r0 + r) * 256 + c0 + x];
        }
        __syncthreads();
#pragma unroll
        for (int j = 0; j < 4; j++) {
            int nn = y + j * 8;
            Wt[(size_t)(c0 + nn) * 256 + r0 + x] = (_Float16)sh[x][nn];
        }
    } else {
        b -= 512;
        int p = b & 7, c = b >> 3;
        int idx = c * 256 + threadIdx.x;
        if (idx >= EPP) return;
        int e = p * EPP + idx;
        int s = ei[e];
        int d = ei[NEDGES + e];
        atomicAdd(&deg_dst[p * NNODES + d], 1);
        atomicAdd(&deg_src[p * NNODES + s], 1);
    }
}

// ---------------- scans ----------------
// y=0: deg_dst -> cur_dst (local exclusive); y=1: deg_src -> cur_src
// y=2: sum_p deg_dst -> mrpl_dst[gid+1] (local inclusive); y=3: same for src

__global__ void scanA_kernel(const int* __restrict__ deg_dst, const int* __restrict__ deg_src,
                             int* __restrict__ cur_dst, int* __restrict__ cur_src,
                             int* __restrict__ mrpl_dst, int* __restrict__ mrpl_src,
                             int* __restrict__ bsum) {
    __shared__ int sh[SCAN_CHUNK];
    const int y = blockIdx.y;
    const int nelem = (y < 2) ? PN : NNODES;
    if (blockIdx.x * SCAN_CHUNK >= nelem) return;
    int t = threadIdx.x;
    int gid = blockIdx.x * SCAN_CHUNK + t;
    int v = 0;
    if (gid < nelem) {
        if (y == 0) v = deg_dst[gid];
        else if (y == 1) v = deg_src[gid];
        else {
            const int* deg = (y == 2) ? deg_dst : deg_src;
#pragma unroll
            for (int p = 0; p < NPART; p++) v += deg[p * NNODES + gid];
        }
    }
    sh[t] = v;
    __syncthreads();
    for (int off = 1; off < SCAN_CHUNK; off <<= 1) {
        int u = (t >= off) ? sh[t - off] : 0;
        __syncthreads();
        sh[t] += u;
        __syncthreads();
    }
    if (gid < nelem) {
        if (y < 2) ((y == 0) ? cur_dst : cur_src)[gid] = sh[t] - v;
        else ((y == 2) ? mrpl_dst : mrpl_src)[gid + 1] = sh[t];
    }
    if (t == SCAN_CHUNK - 1) bsum[y * 256 + blockIdx.x] = sh[t];
}

__global__ void scan2_kernel(int* __restrict__ bsum) {
    int t = threadIdx.x;
    if (t < 4) {
        int cnt = (t < 2) ? NCHUNK2 : NCHUNKM;
        int run = 0;
        for (int i = 0; i < cnt; i++) {
            int v = bsum[t * 256 + i];
            bsum[t * 256 + i] = run;
            run += v;
        }
    }
}

// ---------------- fill (adds chunk base from bsum inline) ----------------

__global__ void fill_kernel(const int* __restrict__ ei, int* __restrict__ cur_dst,
                            int* __restrict__ cur_src, const int* __restrict__ bsum,
                            unsigned short* __restrict__ col_dst,
                            unsigned short* __restrict__ col_src) {
    int p = blockIdx.x & 7, c = blockIdx.x >> 3;
    int idx = c * 256 + threadIdx.x;
    if (idx >= EPP) return;
    int e = p * EPP + idx;
    int s = ei[e];
    int d = ei[NEDGES + e];
    int i0 = p * NNODES + d;
    int p0 = atomicAdd(&cur_dst[i0], 1) + bsum[i0 >> 10];
    col_dst[p0] = (unsigned short)s;
    int i1 = p * NNODES + s;
    int p1 = atomicAdd(&cur_src[i1], 1) + bsum[256 + (i1 >> 10)];
    col_src[p1] = (unsigned short)d;
}

// ---------------- merge (also finalizes mrp) ----------------

__global__ void merge_kernel(const int* __restrict__ deg_dst, const int* __restrict__ deg_src,
                             const int* __restrict__ cur_dst, const int* __restrict__ cur_src,
                             const int* __restrict__ mrpl_dst, const int* __restrict__ mrpl_src,
                             int* __restrict__ mrpf_dst, int* __restrict__ mrpf_src,
                             const int* __restrict__ bsum,
                             const unsigned short* __restrict__ col_dst,
                             const unsigned short* __restrict__ col_src,
                             unsigned short* __restrict__ mcol_dst,
                             unsigned short* __restrict__ mcol_src) {
    const int z = blockIdx.y;
    const int* deg = z ? deg_src : deg_dst;
    const int* cur = z ? cur_src : cur_dst;
    const int* mrpl = z ? mrpl_src : mrpl_dst;
    int* mrpf = z ? mrpf_src : mrpf_dst;
    const unsigned short* col = z ? col_src : col_dst;
    unsigned short* mcol = z ? mcol_src : mcol_dst;
    int n = blockIdx.x * blockDim.x + threadIdx.x;
    if (n >= NNODES) return;
    int dv[NPART];
    int mdeg = 0;
#pragma unroll
    for (int p = 0; p < NPART; p++) {
        dv[p] = deg[p * NNODES + n];
        mdeg += dv[p];
    }
    int start = mrpl[n + 1] + bsum[(2 + z) * 256 + (n >> 10)] - mdeg;
    mrpf[n] = start;
    if (n == NNODES - 1) mrpf[NNODES] = NEDGES;
    int w = start;
#pragma unroll
    for (int p = 0; p < NPART; p++) {
        int i = p * NNODES + n;
        int egl = cur[i] + bsum[z * 256 + (i >> 10)];
        for (int k = egl - dv[p]; k < egl; k++) mcol[w++] = col[k];
    }
}

// ---------------- fp16 MFMA GEMM (BK=32, reg-prefetch, LDS epilogue) ----------------
// y=0: hl_a = xs@Wl[e0];  y=1: hr_a = xt@Wr[e0]
// y=2: hl_b = xt@Wl[e1];  y=3: hr_b = xs@Wr[e1]

__device__ inline half8 ldA8(const _Float16* p) { return *(const half8*)p; }
__device__ inline half8 ldA8(const float* p) {
    float4 a = *(const float4*)p;
    float4 b = *(const float4*)(p + 4);
    half8 r = {(_Float16)a.x, (_Float16)a.y, (_Float16)a.z, (_Float16)a.w,
               (_Float16)b.x, (_Float16)b.y, (_Float16)b.z, (_Float16)b.w};
    return r;
}

#define EPI_STRIDE 264  // halfs

template <typename AT>
__global__ void __launch_bounds__(256)
gemm_f16(const AT* __restrict__ xs, const AT* __restrict__ xt,
         const _Float16* __restrict__ WtL, const _Float16* __restrict__ WtR,
         const float* __restrict__ bl, const float* __restrict__ br,
         _Float16* __restrict__ hbase, int e0) {
    const int y = blockIdx.y;
    const int e = e0 + (y >> 1);
    const AT* A = (y == 0 || y == 3) ? xs : xt;
    const bool left = (y & 1) == 0;
    const _Float16* Wt = (left ? WtL : WtR) + (size_t)e * 65536;
    const float* bvec = (left ? bl : br) + (size_t)e * HC;
    _Float16* C = hbase + (size_t)y * NFE;

    __shared__ __align__(16) _Float16 sh[10240];  // As(2048) | Bs(8192); reused by epilogue
    _Float16* As = sh;
    _Float16* Bs = sh + 2048;

    const int t = threadIdx.x;
    const int lane = t & 63, w = t >> 6;
    const int m0 = blockIdx.x * 64;
    const int rl = lane & 15, ch = lane >> 4;
    const int ar = t >> 2, ac = t & 3;

    floatx4 acc[4][4] = {};

    half8 av = {};
    {
        int gr = m0 + ar;
        if (gr < NNODES) av = ldA8(A + (size_t)gr * 256 + ac * 8);
    }
    half8 bv[4];
#pragma unroll
    for (int j = 0; j < 4; j++)
        bv[j] = *(const half8*)(Wt + (size_t)(ar + j * 64) * 256 + ac * 8);

    for (int k0 = 0; k0 < 256; k0 += 32) {
        __syncthreads();
        *(half8*)(As + ar * 32 + (ac ^ ((ar >> 1) & 3)) * 8) = av;
#pragma unroll
        for (int j = 0; j < 4; j++) {
            int n = ar + j * 64;
            *(half8*)(Bs + n * 32 + (ac ^ ((n >> 1) & 3)) * 8) = bv[j];
        }
        __syncthreads();

        if (k0 + 32 < 256) {
            int gr = m0 + ar;
            if (gr < NNODES) av = ldA8(A + (size_t)gr * 256 + (k0 + 32) + ac * 8);
#pragma unroll
            for (int j = 0; j < 4; j++)
                bv[j] = *(const half8*)(Wt + (size_t)(ar + j * 64) * 256 + (k0 + 32) + ac * 8);
        }

        half8 a[4], b[4];
#pragma unroll
        for (int fm = 0; fm < 4; fm++) {
            int r = fm * 16 + rl;
            a[fm] = *(const half8*)(As + r * 32 + (ch ^ ((r >> 1) & 3)) * 8);
        }
#pragma unroll
        for (int fn = 0; fn < 4; fn++) {
            int n = w * 64 + fn * 16 + rl;
            b[fn] = *(const half8*)(Bs + n * 32 + (ch ^ ((n >> 1) & 3)) * 8);
        }
#pragma unroll
        for (int fm = 0; fm < 4; fm++)
#pragma unroll
            for (int fn = 0; fn < 4; fn++)
                acc[fm][fn] = __builtin_amdgcn_mfma_f32_16x16x32_f16(a[fm], b[fn], acc[fm][fn], 0, 0, 0);
    }

    float bb[4];
#pragma unroll
    for (int fn = 0; fn < 4; fn++) bb[fn] = bvec[w * 64 + fn * 16 + rl];

#pragma unroll
    for (int hh = 0; hh < 2; hh++) {
        __syncthreads();
#pragma unroll
        for (int f2 = 0; f2 < 2; f2++) {
            int fm = hh * 2 + f2;
#pragma unroll
            for (int fn = 0; fn < 4; fn++) {
                int colb = w * 64 + fn * 16 + rl;
#pragma unroll
                for (int j = 0; j < 4; j++) {
                    int lr = f2 * 16 + ch * 4 + j;  // 0..31
                    sh[lr * EPI_STRIDE + colb] = (_Float16)(acc[fm][fn][j] + bb[fn]);
                }
            }
        }
        __syncthreads();
        int lr = t >> 3;            // 0..31
        int cseg = (t & 7) * 32;    // 8 segments x 32 cols (64B)
        int gr = m0 + hh * 32 + lr;
        if (gr < NNODES) {
#pragma unroll
            for (int q = 0; q < 4; q++)
                *(half8*)(C + (size_t)gr * 256 + cseg + q * 8) =
                    *(const half8*)(sh + lr * EPI_STRIDE + cseg + q * 8);
        }
    }
}

// ---------------- fused attention + aggregate (2 edges/wave, 8ch/lane) ----------------
// att pre-scaled by log2(e): logit dot lands in log2 domain -> bare exp2f.

__device__ __forceinline__ void edge_body(half8 hv, half8 hrv, const h2* att2,
                                          float* acc, float& denom, bool valid) {
    const h2 negv = {(_Float16)NEG_SLOPE, (_Float16)NEG_SLOPE};
    const h2* hvp = (const h2*)&hv;
    const h2* hrp = (const h2*)&hrv;
    float v = 0.f;
#pragma unroll
    for (int k = 0; k < 4; k++) {
        h2 x = hvp[k] + hrp[k];
        h2 lk = __builtin_elementwise_max(x, x * negv);
        v = __builtin_amdgcn_fdot2(lk, att2[k], v, false);
    }
    v += __shfl_xor(v, 1);
    v += __shfl_xor(v, 2);
    float pe = exp2f(v);
    if (!valid) pe = 0.f;
    denom += pe;
#pragma unroll
    for (int k = 0; k < 8; k++) acc[k] = fmaf((float)hv[k], pe, acc[k]);
}

__device__ inline void store8(float* p, const float* o) {
    floatx4 v0 = {o[0], o[1], o[2], o[3]};
    floatx4 v1 = {o[4], o[5], o[6], o[7]};
    *(floatx4*)p = v0;
    *(floatx4*)(p + 4) = v1;
}
__device__ inline void store8(_Float16* p, const float* o) {
    half8 h = {(_Float16)o[0], (_Float16)o[1], (_Float16)o[2], (_Float16)o[3],
               (_Float16)o[4], (_Float16)o[5], (_Float16)o[6], (_Float16)o[7]};
    *(half8*)p = h;
}

template <typename OT>
__global__ void __launch_bounds__(256)
agg_kernel(const _Float16* __restrict__ hbase,
           const int* __restrict__ mrp_dst, const unsigned short* __restrict__ mcol_dst,
           const int* __restrict__ mrp_src, const unsigned short* __restrict__ mcol_src,
           const float* __restrict__ att, const float* __restrict__ bias,
           OT* __restrict__ out0, OT* __restrict__ out1, int e0, int do_relu) {
    const int z = blockIdx.y;
    const _Float16* hl = hbase + (size_t)z * 2 * NFE;
    const _Float16* hr = hl + NFE;
    const int* mrp = z ? mrp_src : mrp_dst;
    const unsigned short* mcol = z ? mcol_src : mcol_dst;
    const float* attz = att + (size_t)(e0 + z) * HC;
    const float* biasz = bias + (size_t)(e0 + z) * HC;
    OT* out = z ? out1 : out0;

    int wave = threadIdx.x >> 6;
    int lane = threadIdx.x & 63;
    int n = blockIdx.x * 4 + wave;
    if (n >= NNODES) return;
    int h = lane >> 5;       // edge parity within the wave
    int cl = lane & 31;      // channel block (8 channels)
    int c8 = cl << 3;

    const _Float16* hlc = hl + c8;
    half8 hrv = *(const half8*)(hr + (size_t)n * HC + c8);
    float attf[8];
    *(float4*)(attf) = *(const float4*)(attz + c8);
    *(float4*)(attf + 4) = *(const float4*)(attz + c8 + 4);
    h2 att2[4];
#pragma unroll
    for (int k = 0; k < 4; k++)
        att2[k] = h2{(_Float16)(attf[2 * k] * 1.44269504f),
                     (_Float16)(attf[2 * k + 1] * 1.44269504f)};

    float acc[8] = {};
    float denom = 0.f;
    int beg = mrp[n], end = mrp[n + 1];

    int i = beg;
    for (; i + 4 <= end; i += 4) {
        int s0 = (int)mcol[i + h];
        int s1 = (int)mcol[i + 2 + h];
        half8 hv0 = *(const half8*)(hlc + ((size_t)s0 << 8));
        half8 hv1 = *(const half8*)(hlc + ((size_t)s1 << 8));
        edge_body(hv0, hrv, att2, acc, denom, true);
        edge_body(hv1, hrv, att2, acc, denom, true);
    }
    for (; i < end; i += 2) {
        int ei = i + h;
        bool valid = ei < end;
        int s0 = (int)mcol[valid ? ei : end - 1];
        half8 hv0 = *(const half8*)(hlc + ((size_t)s0 << 8));
        edge_body(hv0, hrv, att2, acc, denom, valid);
    }

    // merge the two half-wave partials
#pragma unroll
    for (int k = 0; k < 8; k++) acc[k] += __shfl_xor(acc[k], 32);
    denom += __shfl_xor(denom, 32);

    if (lane < 32) {
        float inv = 1.f / (denom + 1e-16f);
        float o[8];
        float b8[8];
        *(float4*)(b8) = *(const float4*)(biasz + c8);
        *(float4*)(b8 + 4) = *(const float4*)(biasz + c8 + 4);
#pragma unroll
        for (int k = 0; k < 8; k++) {
            o[k] = acc[k] * inv + b8[k];
            if (do_relu) o[k] = fmaxf(o[k], 0.f);
        }
        store8(out + (size_t)n * HC + c8, o);
    }
}

// ---------------- launch ----------------

extern "C" void kernel_launch(void* const* d_in, const int* in_sizes, int n_in,
                              void* d_out, int out_size, void* d_ws, size_t ws_size,
                              hipStream_t stream) {
    const float* s = (const float*)d_in[0];
    const float* t = (const float*)d_in[1];
    const float* Wl = (const float*)d_in[2];
    const float* bl = (const float*)d_in[3];
    const float* Wr = (const float*)d_in[4];
    const float* br = (const float*)d_in[5];
    const float* att = (const float*)d_in[6];
    const float* bias = (const float*)d_in[7];
    const int* ei = (const int*)d_in[8];
    float* out = (float*)d_out;

    const size_t NF = (size_t)NFE;

    // workspace layout
    _Float16* os16 = (_Float16*)d_ws;         // NF
    _Float16* ot16 = os16 + NF;               // NF
    _Float16* hbase = ot16 + NF;              // 4*NF
    _Float16* WtL = hbase + 4 * NF;           // 4*65536
    _Float16* WtR = WtL + 4 * 65536;          // 4*65536
    int* deg_dst = (int*)(WtR + 4 * 65536);   // PN
    int* deg_src = deg_dst + PN;              // PN
    int* cur_dst = deg_src + PN;              // PN
    int* cur_src = cur_dst + PN;              // PN
    int* mrpl_dst = cur_src + PN;             // N+1
    int* mrpl_src = mrpl_dst + (NNODES + 1);  // N+1
    int* mrpf_dst = mrpl_src + (NNODES + 1);  // N+1
    int* mrpf_src = mrpf_dst + (NNODES + 1);  // N+1
    int* bsum = mrpf_src + (NNODES + 1);      // 1024
    unsigned short* col_dst = (unsigned short*)(bsum + 1024);  // E
    unsigned short* col_src = col_dst + NEDGES;                // E
    unsigned short* mcol_dst = col_src + NEDGES;               // E
    unsigned short* mcol_src = mcol_dst + NEDGES;              // E

    // ---- CSR build + weight prep ----
    hipMemsetAsync(deg_dst, 0, 2 * PN * sizeof(int), stream);
    prep_kernel<<<512 + NPART * CPP, 256, 0, stream>>>(Wl, Wr, WtL, WtR, ei, deg_dst, deg_src);
    scanA_kernel<<<dim3(NCHUNK2, 4), SCAN_CHUNK, 0, stream>>>(deg_dst, deg_src, cur_dst, cur_src,
                                                              mrpl_dst, mrpl_src, bsum);
    scan2_kernel<<<1, 64, 0, stream>>>(bsum);
    fill_kernel<<<NPART * CPP, 256, 0, stream>>>(ei, cur_dst, cur_src, bsum, col_dst, col_src);
    merge_kernel<<<dim3(118, 2), 256, 0, stream>>>(deg_dst, deg_src, cur_dst, cur_src,
                                                   mrpl_dst, mrpl_src, mrpf_dst, mrpf_src, bsum,
                                                   col_dst, col_src, mcol_dst, mcol_src);

    dim3 ggemm((NNODES + 63) / 64, 4);
    dim3 gagg((NNODES + 3) / 4, 2);

    // layer 0 (fp32 inputs, relu)
    gemm_f16<float><<<ggemm, 256, 0, stream>>>(s, t, WtL, WtR, bl, br, hbase, 0);
    agg_kernel<_Float16><<<gagg, 256, 0, stream>>>(hbase, mrpf_dst, mcol_dst, mrpf_src, mcol_src,
                                                   att, bias, os16, ot16, 0, 1);
    // layer 1 (fp16 inputs, identity, fp32 out)
    gemm_f16<_Float16><<<ggemm, 256, 0, stream>>>(os16, ot16, WtL, WtR, bl, br, hbase, 2);
    agg_kernel<float><<<gagg, 256, 0, stream>>>(hbase, mrpf_dst, mcol_dst, mrpf_src, mcol_src,
                                                att, bias, out, out + NF, 2, 0);
}

// Round 15
// 338.209 us; speedup vs baseline: 1.1938x; 1.0688x over previous
//
#include <hip/hip_runtime.h>
#include <hip/hip_bf16.h>

#define NNODES 30000
#define NEDGES 480000
#define HC 256
#define NEG_SLOPE 0.2f
#define NPART 8
#define EPP 60000                 // NEDGES / NPART
#define PN (NPART * NNODES)       // 240000
#define SCAN_CHUNK 1024
#define NCHUNK2 235               // ceil(PN / 1024)
#define NCHUNKM 30                // ceil(NNODES / 1024)
#define CPP 235                   // ceil(EPP / 256)
#define NFE 7680000               // NNODES * HC

typedef _Float16 half8 __attribute__((ext_vector_type(8)));
typedef _Float16 h4v __attribute__((ext_vector_type(4)));
typedef _Float16 h2 __attribute__((ext_vector_type(2)));
typedef float floatx4 __attribute__((ext_vector_type(4)));

// ---------------- prep: weight transpose+cvt (blocks 0..511) | edge histogram (rest) ----------------

__global__ void prep_kernel(const float* __restrict__ Wl, const float* __restrict__ Wr,
                            _Float16* __restrict__ WtL, _Float16* __restrict__ WtR,
                            const int* __restrict__ ei, int* __restrict__ deg_dst,
                            int* __restrict__ deg_src) {
    __shared__ float sh[32][33];
    int b = blockIdx.x;
    if (b < 512) {
        int e = b >> 6;
        int r0 = ((b >> 3) & 7) * 32, c0 = (b & 7) * 32;
        const float* W = (e < 4) ? Wl + (size_t)e * 65536 : Wr + (size_t)(e - 4) * 65536;
        _Float16* Wt = (e < 4) ? WtL + (size_t)e * 65536 : WtR + (size_t)(e - 4) * 65536;
        int x = threadIdx.x & 31, y = threadIdx.x >> 5;  // 32 x 8
#pragma unroll
        for (int j = 0; j < 4; j++) {
            int r = y + j * 8;
            sh[r][x] = W[(size_t)(r0 + r) * 256 + c0 + x];
        }
        __syncthreads();
#pragma unroll
        for (int j = 0; j < 4; j++) {
            int nn = y + j * 8;
            Wt[(size_t)(c0 + nn) * 256 + r0 + x] = (_Float16)sh[x][nn];
        }
    } else {
        b -= 512;
        int p = b & 7, c = b >> 3;
        int idx = c * 256 + threadIdx.x;
        if (idx >= EPP) return;
        int e = p * EPP + idx;
        int s = ei[e];
        int d = ei[NEDGES + e];
        atomicAdd(&deg_dst[p * NNODES + d], 1);
        atomicAdd(&deg_src[p * NNODES + s], 1);
    }
}

// ---------------- scans ----------------
// y=0: deg_dst -> cur_dst (local exclusive); y=1: deg_src -> cur_src
// y=2: sum_p deg_dst -> mrpl_dst[gid+1] (local inclusive); y=3: same for src

__global__ void scanA_kernel(const int* __restrict__ deg_dst, const int* __restrict__ deg_src,
                             int* __restrict__ cur_dst, int* __restrict__ cur_src,
                             int* __restrict__ mrpl_dst, int* __restrict__ mrpl_src,
                             int* __restrict__ bsum) {
    __shared__ int sh[SCAN_CHUNK];
    const int y = blockIdx.y;
    const int nelem = (y < 2) ? PN : NNODES;
    if (blockIdx.x * SCAN_CHUNK >= nelem) return;
    int t = threadIdx.x;
    int gid = blockIdx.x * SCAN_CHUNK + t;
    int v = 0;
    if (gid < nelem) {
        if (y == 0) v = deg_dst[gid];
        else if (y == 1) v = deg_src[gid];
        else {
            const int* deg = (y == 2) ? deg_dst : deg_src;
#pragma unroll
            for (int p = 0; p < NPART; p++) v += deg[p * NNODES + gid];
        }
    }
    sh[t] = v;
    __syncthreads();
    for (int off = 1; off < SCAN_CHUNK; off <<= 1) {
        int u = (t >= off) ? sh[t - off] : 0;
        __syncthreads();
        sh[t] += u;
        __syncthreads();
    }
    if (gid < nelem) {
        if (y < 2) ((y == 0) ? cur_dst : cur_src)[gid] = sh[t] - v;
        else ((y == 2) ? mrpl_dst : mrpl_src)[gid + 1] = sh[t];
    }
    if (t == SCAN_CHUNK - 1) bsum[y * 256 + blockIdx.x] = sh[t];
}

// parallel base scan: 1024 threads = 4 rows x 256 entries, Hillis-Steele in LDS,
// writes back EXCLUSIVE bases (replaces the 4-lane serial loop).
__global__ void scan2_kernel(int* __restrict__ bsum) {
    __shared__ int sh[4][256];
    int t = threadIdx.x;
    int row = t >> 8, i = t & 255;
    int cnt = (row < 2) ? NCHUNK2 : NCHUNKM;
    int v = (i < cnt) ? bsum[row * 256 + i] : 0;
    sh[row][i] = v;
    __syncthreads();
    for (int off = 1; off < 256; off <<= 1) {
        int u = (i >= off) ? sh[row][i - off] : 0;
        __syncthreads();
        sh[row][i] += u;
        __syncthreads();
    }
    if (i < cnt) bsum[row * 256 + i] = sh[row][i] - v;  // exclusive
}

// ---------------- fill (adds chunk base from bsum inline) ----------------

__global__ void fill_kernel(const int* __restrict__ ei, int* __restrict__ cur_dst,
                            int* __restrict__ cur_src, const int* __restrict__ bsum,
                            unsigned short* __restrict__ col_dst,
                            unsigned short* __restrict__ col_src) {
    int p = blockIdx.x & 7, c = blockIdx.x >> 3;
    int idx = c * 256 + threadIdx.x;
    if (idx >= EPP) return;
    int e = p * EPP + idx;
    int s = ei[e];
    int d = ei[NEDGES + e];
    int i0 = p * NNODES + d;
    int p0 = atomicAdd(&cur_dst[i0], 1) + bsum[i0 >> 10];
    col_dst[p0] = (unsigned short)s;
    int i1 = p * NNODES + s;
    int p1 = atomicAdd(&cur_src[i1], 1) + bsum[256 + (i1 >> 10)];
    col_src[p1] = (unsigned short)d;
}

// ---------------- merge (also finalizes mrp) ----------------

__global__ void merge_kernel(const int* __restrict__ deg_dst, const int* __restrict__ deg_src,
                             const int* __restrict__ cur_dst, const int* __restrict__ cur_src,
                             const int* __restrict__ mrpl_dst, const int* __restrict__ mrpl_src,
                             int* __restrict__ mrpf_dst, int* __restrict__ mrpf_src,
                             const int* __restrict__ bsum,
                             const unsigned short* __restrict__ col_dst,
                             const unsigned short* __restrict__ col_src,
                             unsigned short* __restrict__ mcol_dst,
                             unsigned short* __restrict__ mcol_src) {
    const int z = blockIdx.y;
    const int* deg = z ? deg_src : deg_dst;
    const int* cur = z ? cur_src : cur_dst;
    const int* mrpl = z ? mrpl_src : mrpl_dst;
    int* mrpf = z ? mrpf_src : mrpf_dst;
    const unsigned short* col = z ? col_src : col_dst;
    unsigned short* mcol = z ? mcol_src : mcol_dst;
    int n = blockIdx.x * blockDim.x + threadIdx.x;
    if (n >= NNODES) return;
    int dv[NPART];
    int mdeg = 0;
#pragma unroll
    for (int p = 0; p < NPART; p++) {
        dv[p] = deg[p * NNODES + n];
        mdeg += dv[p];
    }
    int start = mrpl[n + 1] + bsum[(2 + z) * 256 + (n >> 10)] - mdeg;
    mrpf[n] = start;
    if (n == NNODES - 1) mrpf[NNODES] = NEDGES;
    int w = start;
#pragma unroll
    for (int p = 0; p < NPART; p++) {
        int i = p * NNODES + n;
        int egl = cur[i] + bsum[z * 256 + (i >> 10)];
        for (int k = egl - dv[p]; k < egl; k++) mcol[w++] = col[k];
    }
}

// ---------------- fp16 MFMA GEMM (BK=32, reg-prefetch, LDS epilogue) ----------------
// y=0: hl_a = xs@Wl[e0];  y=1: hr_a = xt@Wr[e0]
// y=2: hl_b = xt@Wl[e1];  y=3: hr_b = xs@Wr[e1]

__device__ inline half8 ldA8(const _Float16* p) { return *(const half8*)p; }
__device__ inline half8 ldA8(const float* p) {
    float4 a = *(const float4*)p;
    float4 b = *(const float4*)(p + 4);
    half8 r = {(_Float16)a.x, (_Float16)a.y, (_Float16)a.z, (_Float16)a.w,
               (_Float16)b.x, (_Float16)b.y, (_Float16)b.z, (_Float16)b.w};
    return r;
}

#define EPI_STRIDE 264  // halfs

template <typename AT>
__global__ void __launch_bounds__(256)
gemm_f16(const AT* __restrict__ xs, const AT* __restrict__ xt,
         const _Float16* __restrict__ WtL, const _Float16* __restrict__ WtR,
         const float* __restrict__ bl, const float* __restrict__ br,
         _Float16* __restrict__ hbase, int e0) {
    const int y = blockIdx.y;
    const int e = e0 + (y >> 1);
    const AT* A = (y == 0 || y == 3) ? xs : xt;
    const bool left = (y & 1) == 0;
    const _Float16* Wt = (left ? WtL : WtR) + (size_t)e * 65536;
    const float* bvec = (left ? bl : br) + (size_t)e * HC;
    _Float16* C = hbase + (size_t)y * NFE;

    __shared__ __align__(16) _Float16 sh[10240];  // As(2048) | Bs(8192); reused by epilogue
    _Float16* As = sh;
    _Float16* Bs = sh + 2048;

    const int t = threadIdx.x;
    const int lane = t & 63, w = t >> 6;
    const int m0 = blockIdx.x * 64;
    const int rl = lane & 15, ch = lane >> 4;
    const int ar = t >> 2, ac = t & 3;

    floatx4 acc[4][4] = {};

    half8 av = {};
    {
        int gr = m0 + ar;
        if (gr < NNODES) av = ldA8(A + (size_t)gr * 256 + ac * 8);
    }
    half8 bv[4];
#pragma unroll
    for (int j = 0; j < 4; j++)
        bv[j] = *(const half8*)(Wt + (size_t)(ar + j * 64) * 256 + ac * 8);

    for (int k0 = 0; k0 < 256; k0 += 32) {
        __syncthreads();
        *(half8*)(As + ar * 32 + (ac ^ ((ar >> 1) & 3)) * 8) = av;
#pragma unroll
        for (int j = 0; j < 4; j++) {
            int n = ar + j * 64;
            *(half8*)(Bs + n * 32 + (ac ^ ((n >> 1) & 3)) * 8) = bv[j];
        }
        __syncthreads();

        if (k0 + 32 < 256) {
            int gr = m0 + ar;
            if (gr < NNODES) av = ldA8(A + (size_t)gr * 256 + (k0 + 32) + ac * 8);
#pragma unroll
            for (int j = 0; j < 4; j++)
                bv[j] = *(const half8*)(Wt + (size_t)(ar + j * 64) * 256 + (k0 + 32) + ac * 8);
        }

        half8 a[4], b[4];
#pragma unroll
        for (int fm = 0; fm < 4; fm++) {
            int r = fm * 16 + rl;
            a[fm] = *(const half8*)(As + r * 32 + (ch ^ ((r >> 1) & 3)) * 8);
        }
#pragma unroll
        for (int fn = 0; fn < 4; fn++) {
            int n = w * 64 + fn * 16 + rl;
            b[fn] = *(const half8*)(Bs + n * 32 + (ch ^ ((n >> 1) & 3)) * 8);
        }
#pragma unroll
        for (int fm = 0; fm < 4; fm++)
#pragma unroll
            for (int fn = 0; fn < 4; fn++)
                acc[fm][fn] = __builtin_amdgcn_mfma_f32_16x16x32_f16(a[fm], b[fn], acc[fm][fn], 0, 0, 0);
    }

    float bb[4];
#pragma unroll
    for (int fn = 0; fn < 4; fn++) bb[fn] = bvec[w * 64 + fn * 16 + rl];

#pragma unroll
    for (int hh = 0; hh < 2; hh++) {
        __syncthreads();
#pragma unroll
        for (int f2 = 0; f2 < 2; f2++) {
            int fm = hh * 2 + f2;
#pragma unroll
            for (int fn = 0; fn < 4; fn++) {
                int colb = w * 64 + fn * 16 + rl;
#pragma unroll
                for (int j = 0; j < 4; j++) {
                    int lr = f2 * 16 + ch * 4 + j;  // 0..31
                    sh[lr * EPI_STRIDE + colb] = (_Float16)(acc[fm][fn][j] + bb[fn]);
                }
            }
        }
        __syncthreads();
        int lr = t >> 3;            // 0..31
        int cseg = (t & 7) * 32;    // 8 segments x 32 cols (64B)
        int gr = m0 + hh * 32 + lr;
        if (gr < NNODES) {
#pragma unroll
            for (int q = 0; q < 4; q++)
                *(half8*)(C + (size_t)gr * 256 + cseg + q * 8) =
                    *(const half8*)(sh + lr * EPI_STRIDE + cseg + q * 8);
        }
    }
}

// ---------------- fused attention + aggregate (2 edges/wave, 8ch/lane) ----------------
// att pre-scaled by log2(e): logit dot lands in log2 domain -> bare exp2f.

__device__ __forceinline__ void edge_body(half8 hv, half8 hrv, const h2* att2,
                                          float* acc, float& denom, bool valid) {
    const h2 negv = {(_Float16)NEG_SLOPE, (_Float16)NEG_SLOPE};
    const h2* hvp = (const h2*)&hv;
    const h2* hrp = (const h2*)&hrv;
    float v = 0.f;
#pragma unroll
    for (int k = 0; k < 4; k++) {
        h2 x = hvp[k] + hrp[k];
        h2 lk = __builtin_elementwise_max(x, x * negv);
        v = __builtin_amdgcn_fdot2(lk, att2[k], v, false);
    }
    v += __shfl_xor(v, 1);
    v += __shfl_xor(v, 2);
    float pe = exp2f(v);
    if (!valid) pe = 0.f;
    denom += pe;
#pragma unroll
    for (int k = 0; k < 8; k++) acc[k] = fmaf((float)hv[k], pe, acc[k]);
}

__device__ inline void store8(float* p, const float* o) {
    floatx4 v0 = {o[0], o[1], o[2], o[3]};
    floatx4 v1 = {o[4], o[5], o[6], o[7]};
    *(floatx4*)p = v0;
    *(floatx4*)(p + 4) = v1;
}
__device__ inline void store8(_Float16* p, const float* o) {
    half8 h = {(_Float16)o[0], (_Float16)o[1], (_Float16)o[2], (_Float16)o[3],
               (_Float16)o[4], (_Float16)o[5], (_Float16)o[6], (_Float16)o[7]};
    *(half8*)p = h;
}

template <typename OT>
__global__ void __launch_bounds__(256)
agg_kernel(const _Float16* __restrict__ hbase,
           const int* __restrict__ mrp_dst, const unsigned short* __restrict__ mcol_dst,
           const int* __restrict__ mrp_src, const unsigned short* __restrict__ mcol_src,
           const float* __restrict__ att, const float* __restrict__ bias,
           OT* __restrict__ out0, OT* __restrict__ out1, int e0, int do_relu) {
    const int z = blockIdx.y;
    const _Float16* hl = hbase + (size_t)z * 2 * NFE;
    const _Float16* hr = hl + NFE;
    const int* mrp = z ? mrp_src : mrp_dst;
    const unsigned short* mcol = z ? mcol_src : mcol_dst;
    const float* attz = att + (size_t)(e0 + z) * HC;
    const float* biasz = bias + (size_t)(e0 + z) * HC;
    OT* out = z ? out1 : out0;

    int wave = threadIdx.x >> 6;
    int lane = threadIdx.x & 63;
    int n = blockIdx.x * 4 + wave;
    if (n >= NNODES) return;
    int h = lane >> 5;       // edge parity within the wave
    int cl = lane & 31;      // channel block (8 channels)
    int c8 = cl << 3;

    const _Float16* hlc = hl + c8;
    half8 hrv = *(const half8*)(hr + (size_t)n * HC + c8);
    float attf[8];
    *(float4*)(attf) = *(const float4*)(attz + c8);
    *(float4*)(attf + 4) = *(const float4*)(attz + c8 + 4);
    h2 att2[4];
#pragma unroll
    for (int k = 0; k < 4; k++)
        att2[k] = h2{(_Float16)(attf[2 * k] * 1.44269504f),
                     (_Float16)(attf[2 * k + 1] * 1.44269504f)};

    float acc[8] = {};
    float denom = 0.f;
    int beg = mrp[n], end = mrp[n + 1];

    int i = beg;
    for (; i + 4 <= end; i += 4) {
        int s0 = (int)mcol[i + h];
        int s1 = (int)mcol[i + 2 + h];
        half8 hv0 = *(const half8*)(hlc + ((size_t)s0 << 8));
        half8 hv1 = *(const half8*)(hlc + ((size_t)s1 << 8));
        edge_body(hv0, hrv, att2, acc, denom, true);
        edge_body(hv1, hrv, att2, acc, denom, true);
    }
    for (; i < end; i += 2) {
        int ei = i + h;
        bool valid = ei < end;
        int s0 = (int)mcol[valid ? ei : end - 1];
        half8 hv0 = *(const half8*)(hlc + ((size_t)s0 << 8));
        edge_body(hv0, hrv, att2, acc, denom, valid);
    }

    // merge the two half-wave partials
#pragma unroll
    for (int k = 0; k < 8; k++) acc[k] += __shfl_xor(acc[k], 32);
    denom += __shfl_xor(denom, 32);

    if (lane < 32) {
        float inv = 1.f / (denom + 1e-16f);
        float o[8];
        float b8[8];
        *(float4*)(b8) = *(const float4*)(biasz + c8);
        *(float4*)(b8 + 4) = *(const float4*)(biasz + c8 + 4);
#pragma unroll
        for (int k = 0; k < 8; k++) {
            o[k] = acc[k] * inv + b8[k];
            if (do_relu) o[k] = fmaxf(o[k], 0.f);
        }
        store8(out + (size_t)n * HC + c8, o);
    }
}

// ---------------- launch ----------------

extern "C" void kernel_launch(void* const* d_in, const int* in_sizes, int n_in,
                              void* d_out, int out_size, void* d_ws, size_t ws_size,
                              hipStream_t stream) {
    const float* s = (const float*)d_in[0];
    const float* t = (const float*)d_in[1];
    const float* Wl = (const float*)d_in[2];
    const float* bl = (const float*)d_in[3];
    const float* Wr = (const float*)d_in[4];
    const float* br = (const float*)d_in[5];
    const float* att = (const float*)d_in[6];
    const float* bias = (const float*)d_in[7];
    const int* ei = (const int*)d_in[8];
    float* out = (float*)d_out;

    const size_t NF = (size_t)NFE;

    // workspace layout
    _Float16* os16 = (_Float16*)d_ws;         // NF
    _Float16* ot16 = os16 + NF;               // NF
    _Float16* hbase = ot16 + NF;              // 4*NF
    _Float16* WtL = hbase + 4 * NF;           // 4*65536
    _Float16* WtR = WtL + 4 * 65536;          // 4*65536
    int* deg_dst = (int*)(WtR + 4 * 65536);   // PN
    int* deg_src = deg_dst + PN;              // PN
    int* cur_dst = deg_src + PN;              // PN
    int* cur_src = cur_dst + PN;              // PN
    int* mrpl_dst = cur_src + PN;             // N+1
    int* mrpl_src = mrpl_dst + (NNODES + 1);  // N+1
    int* mrpf_dst = mrpl_src + (NNODES + 1);  // N+1
    int* mrpf_src = mrpf_dst + (NNODES + 1);  // N+1
    int* bsum = mrpf_src + (NNODES + 1);      // 1024
    unsigned short* col_dst = (unsigned short*)(bsum + 1024);  // E
    unsigned short* col_src = col_dst + NEDGES;                // E
    unsigned short* mcol_dst = col_src + NEDGES;               // E
    unsigned short* mcol_src = mcol_dst + NEDGES;              // E

    // ---- CSR build + weight prep ----
    hipMemsetAsync(deg_dst, 0, 2 * PN * sizeof(int), stream);
    prep_kernel<<<512 + NPART * CPP, 256, 0, stream>>>(Wl, Wr, WtL, WtR, ei, deg_dst, deg_src);
    scanA_kernel<<<dim3(NCHUNK2, 4), SCAN_CHUNK, 0, stream>>>(deg_dst, deg_src, cur_dst, cur_src,
                                                              mrpl_dst, mrpl_src, bsum);
    scan2_kernel<<<1, 1024, 0, stream>>>(bsum);
    fill_kernel<<<NPART * CPP, 256, 0, stream>>>(ei, cur_dst, cur_src, bsum, col_dst, col_src);
    merge_kernel<<<dim3(118, 2), 256, 0, stream>>>(deg_dst, deg_src, cur_dst, cur_src,
                                                   mrpl_dst, mrpl_src, mrpf_dst, mrpf_src, bsum,
                                                   col_dst, col_src, mcol_dst, mcol_src);

    dim3 ggemm((NNODES + 63) / 64, 4);
    dim3 gagg((NNODES + 3) / 4, 2);

    // layer 0 (fp32 inputs, relu)
    gemm_f16<float><<<ggemm, 256, 0, stream>>>(s, t, WtL, WtR, bl, br, hbase, 0);
    agg_kernel<_Float16><<<gagg, 256, 0, stream>>>(hbase, mrpf_dst, mcol_dst, mrpf_src, mcol_src,
                                                   att, bias, os16, ot16, 0, 1);
    // layer 1 (fp16 inputs, identity, fp32 out)
    gemm_f16<_Float16><<<ggemm, 256, 0, stream>>>(os16, ot16, WtL, WtR, bl, br, hbase, 2);
    agg_kernel<float><<<gagg, 256, 0, stream>>>(hbase, mrpf_dst, mcol_dst, mrpf_src, mcol_src,
                                                att, bias, out, out + NF, 2, 0);
}